// Round 1
// baseline (248.327 us; speedup 1.0000x reference)
//
#include <hip/hip_runtime.h>
#include <hip/hip_bf16.h>

#define NNODES_MAX 100000

typedef __attribute__((ext_vector_type(8))) short short8;
typedef __attribute__((ext_vector_type(4))) float f32x4;

__device__ __forceinline__ unsigned short f2bf(float x) {
    unsigned int u = __float_as_uint(x);
    unsigned int lsb = (u >> 16) & 1u;
    u += 0x7fffu + lsb;                    // round-to-nearest-even
    return (unsigned short)(u >> 16);
}

__device__ __forceinline__ float bf2f(unsigned short b) {
    return __uint_as_float(((unsigned int)b) << 16);
}

__device__ __forceinline__ short8 pack8(float4 a, float4 b) {
    short8 r;
    r[0] = (short)f2bf(a.x); r[1] = (short)f2bf(a.y);
    r[2] = (short)f2bf(a.z); r[3] = (short)f2bf(a.w);
    r[4] = (short)f2bf(b.x); r[5] = (short)f2bf(b.y);
    r[6] = (short)f2bf(b.z); r[7] = (short)f2bf(b.w);
    return r;
}

// out[n][c] = b[c] for all n (handles zero-degree rows; atomics add on top)
__global__ __launch_bounds__(256) void k_init(const float* __restrict__ bias,
                                              float* __restrict__ out, int total) {
    int i = blockIdx.x * 256 + threadIdx.x;
    if (i < total) out[i] = bias[i & 63];
}

// G[n][c] = sum_f feat[n][f] * W[c][f], bf16 MFMA, G stored as bf16 bits.
// One wave per 16-node tile. K=64 -> 2 k-steps of 32. C=64 -> 4 col-tiles of 16.
__global__ __launch_bounds__(256) void k_gemm(const float* __restrict__ feat,
                                              const float* __restrict__ W,
                                              unsigned short* __restrict__ G, int N) {
    int wave = blockIdx.x * 4 + (threadIdx.x >> 6);
    int lane = threadIdx.x & 63;
    int m0 = wave * 16;
    if (m0 >= N) return;
    int n = lane & 15;        // col within 16 (A: row m; B: col n; D: col)
    int quad = lane >> 4;     // k-chunk selector / D row-group

    // B fragments: B[k][c0+n] = W[c0+n][k]; lane n holds W row (c0+n),
    // k = ks*32 + quad*8 + j  -> contiguous 8 floats in W's row.
    short8 bf[4][2];
#pragma unroll
    for (int ct = 0; ct < 4; ++ct)
#pragma unroll
        for (int ks = 0; ks < 2; ++ks) {
            const float* wp = W + (size_t)(ct * 16 + n) * 64 + ks * 32 + quad * 8;
            float4 w0 = *(const float4*)wp;
            float4 w1 = *(const float4*)(wp + 4);
            bf[ct][ks] = pack8(w0, w1);
        }

    // A fragments: A[m0+n][k], k = ks*32 + quad*8 + j -> contiguous 8 floats.
    int mrow = m0 + n; if (mrow >= N) mrow = N - 1;   // clamp (tail safety)
    short8 af[2];
#pragma unroll
    for (int ks = 0; ks < 2; ++ks) {
        const float* ap = feat + (size_t)mrow * 64 + ks * 32 + quad * 8;
        float4 a0 = *(const float4*)ap;
        float4 a1 = *(const float4*)(ap + 4);
        af[ks] = pack8(a0, a1);
    }

    f32x4 acc[4];
#pragma unroll
    for (int ct = 0; ct < 4; ++ct) {
        acc[ct] = (f32x4){0.f, 0.f, 0.f, 0.f};
#pragma unroll
        for (int ks = 0; ks < 2; ++ks)
            acc[ct] = __builtin_amdgcn_mfma_f32_16x16x32_bf16(af[ks], bf[ct][ks], acc[ct], 0, 0, 0);
    }

    // D layout: col = lane&15 (=n), row = quad*4 + reg
#pragma unroll
    for (int ct = 0; ct < 4; ++ct)
#pragma unroll
        for (int r = 0; r < 4; ++r) {
            int rowm = m0 + quad * 4 + r;
            if (rowm < N)
                G[(size_t)rowm * 64 + ct * 16 + n] = f2bf(acc[ct][r]);
        }
}

// SpMM: out[row] += val * G[col]. Sorted rows -> register accumulate, flush on
// row change via one atomicAdd wave-op. lane = channel.
__global__ __launch_bounds__(256) void k_spmm(const unsigned short* __restrict__ G,
                                              const int* __restrict__ erow,
                                              const int* __restrict__ ecol,
                                              const float* __restrict__ evalv,
                                              float* __restrict__ out,
                                              int E, int epw) {
    int wave = blockIdx.x * 4 + (threadIdx.x >> 6);
    int lane = threadIdx.x & 63;
    long e0 = (long)wave * epw;
    if (e0 >= E) return;
    long e1 = e0 + epw; if (e1 > E) e1 = E;

    int cur = erow[e0];
    float acc = 0.f;
    for (long e = e0; e < e1; ++e) {
        int r = erow[e];
        int c = ecol[e];
        float v = evalv[e];
        float g = bf2f(G[((size_t)c << 6) | lane]);   // coalesced 128B gather
        if (r != cur) {                               // wave-uniform branch
            atomicAdd(out + ((size_t)cur << 6) + lane, acc);
            acc = 0.f;
            cur = r;
        }
        acc += v * g;
    }
    atomicAdd(out + ((size_t)cur << 6) + lane, acc);
}

// Fallback if ws too small: fused — gather feat f32, transform at flush via shfl + LDS W.
__global__ __launch_bounds__(256) void k_fused(const float* __restrict__ feat,
                                               const int* __restrict__ erow,
                                               const int* __restrict__ ecol,
                                               const float* __restrict__ evalv,
                                               const float* __restrict__ W,
                                               float* __restrict__ out,
                                               int E, int epw) {
    __shared__ float Wt[64 * 64];   // Wt[f*64+c] = W[c][f]
    for (int i = threadIdx.x; i < 4096; i += 256) {
        int c = i >> 6, f = i & 63;
        Wt[f * 64 + c] = W[i];
    }
    __syncthreads();

    int wave = blockIdx.x * 4 + (threadIdx.x >> 6);
    int lane = threadIdx.x & 63;
    long e0 = (long)wave * epw;
    if (e0 >= E) return;
    long e1 = e0 + epw; if (e1 > E) e1 = E;

    int cur = erow[e0];
    float acc = 0.f;   // lane = feature f
    for (long e = e0; e < e1; ++e) {
        int r = erow[e];
        int c = ecol[e];
        float v = evalv[e];
        float g = feat[((size_t)c << 6) | lane];
        if (r != cur) {
            float res = 0.f;
#pragma unroll
            for (int f = 0; f < 64; ++f)
                res += __shfl(acc, f, 64) * Wt[f * 64 + lane];
            atomicAdd(out + ((size_t)cur << 6) + lane, res);
            acc = 0.f;
            cur = r;
        }
        acc += v * g;
    }
    {
        float res = 0.f;
#pragma unroll
        for (int f = 0; f < 64; ++f)
            res += __shfl(acc, f, 64) * Wt[f * 64 + lane];
        atomicAdd(out + ((size_t)cur << 6) + lane, res);
    }
}

extern "C" void kernel_launch(void* const* d_in, const int* in_sizes, int n_in,
                              void* d_out, int out_size, void* d_ws, size_t ws_size,
                              hipStream_t stream) {
    const float* feat  = (const float*)d_in[0];
    const int*   erow  = (const int*)d_in[1];
    const int*   ecol  = (const int*)d_in[2];
    const float* evalv = (const float*)d_in[3];
    const float* W     = (const float*)d_in[4];
    const float* bias  = (const float*)d_in[5];
    float* out = (float*)d_out;

    int N = in_sizes[0] / 64;
    int E = in_sizes[1];

    // out = bias (broadcast)
    int total = N * 64;
    k_init<<<(total + 255) / 256, 256, 0, stream>>>(bias, out, total);

    // target ~8192 waves for the edge pass
    int epw = (E + 8191) / 8192;
    if (epw < 32) epw = 32;
    int nwaves = (E + epw - 1) / epw;
    int nblocks = (nwaves + 3) / 4;

    size_t need = (size_t)N * 64 * sizeof(unsigned short);
    if (ws_size >= need) {
        unsigned short* G = (unsigned short*)d_ws;
        int tiles = (N + 15) / 16;
        int gblocks = (tiles + 3) / 4;
        k_gemm<<<gblocks, 256, 0, stream>>>(feat, W, G, N);
        k_spmm<<<nblocks, 256, 0, stream>>>(G, erow, ecol, evalv, out, E, epw);
    } else {
        k_fused<<<nblocks, 256, 0, stream>>>(feat, erow, ecol, evalv, W, out, E, epw);
    }
}

// Round 2
// 141.845 us; speedup vs baseline: 1.7507x; 1.7507x over previous
//
#include <hip/hip_runtime.h>
#include <hip/hip_bf16.h>

typedef __attribute__((ext_vector_type(8))) short short8;
typedef __attribute__((ext_vector_type(4))) float f32x4;

__device__ __forceinline__ unsigned short f2bf(float x) {
    unsigned int u = __float_as_uint(x);
    unsigned int lsb = (u >> 16) & 1u;
    u += 0x7fffu + lsb;                    // round-to-nearest-even
    return (unsigned short)(u >> 16);
}

__device__ __forceinline__ float bf2f(unsigned short b) {
    return __uint_as_float(((unsigned int)b) << 16);
}

__device__ __forceinline__ short8 pack8(float4 a, float4 b) {
    short8 r;
    r[0] = (short)f2bf(a.x); r[1] = (short)f2bf(a.y);
    r[2] = (short)f2bf(a.z); r[3] = (short)f2bf(a.w);
    r[4] = (short)f2bf(b.x); r[5] = (short)f2bf(b.y);
    r[6] = (short)f2bf(b.z); r[7] = (short)f2bf(b.w);
    return r;
}

// Standalone init (fallback path): out[n][c] = bias[c]
__global__ __launch_bounds__(256) void k_init(const float* __restrict__ bias,
                                              float* __restrict__ out, long total4) {
    long i4 = (long)blockIdx.x * 256 + threadIdx.x;
    if (i4 < total4) {
        const float4* b4 = (const float4*)bias;
        ((float4*)out)[i4] = b4[i4 & 15];
    }
}

// Fused: blocks [0,gblocks) compute G = (feat @ W.T) in bf16 via MFMA;
// blocks [gblocks, ...) broadcast bias into out (float4).
__global__ __launch_bounds__(256) void k_setup(const float* __restrict__ feat,
                                               const float* __restrict__ W,
                                               const float* __restrict__ bias,
                                               unsigned short* __restrict__ G,
                                               float* __restrict__ out,
                                               int N, int gblocks) {
    if ((int)blockIdx.x >= gblocks) {
        long i4 = (long)(blockIdx.x - gblocks) * 256 + threadIdx.x;
        long total4 = (long)N * 16;            // N*64 floats / 4
        if (i4 < total4) {
            const float4* b4 = (const float4*)bias;
            ((float4*)out)[i4] = b4[i4 & 15];
        }
        return;
    }

    int wave = blockIdx.x * 4 + (threadIdx.x >> 6);
    int lane = threadIdx.x & 63;
    int m0 = wave * 16;
    if (m0 >= N) return;
    int n = lane & 15;
    int quad = lane >> 4;

    // B fragments: B[k][c0+n] = W[c0+n][k]; k = ks*32 + quad*8 + j
    short8 bf[4][2];
#pragma unroll
    for (int ct = 0; ct < 4; ++ct)
#pragma unroll
        for (int ks = 0; ks < 2; ++ks) {
            const float* wp = W + (size_t)(ct * 16 + n) * 64 + ks * 32 + quad * 8;
            float4 w0 = *(const float4*)wp;
            float4 w1 = *(const float4*)(wp + 4);
            bf[ct][ks] = pack8(w0, w1);
        }

    // A fragments: A[m0+n][k]
    int mrow = m0 + n; if (mrow >= N) mrow = N - 1;
    short8 af[2];
#pragma unroll
    for (int ks = 0; ks < 2; ++ks) {
        const float* ap = feat + (size_t)mrow * 64 + ks * 32 + quad * 8;
        float4 a0 = *(const float4*)ap;
        float4 a1 = *(const float4*)(ap + 4);
        af[ks] = pack8(a0, a1);
    }

    f32x4 acc[4];
#pragma unroll
    for (int ct = 0; ct < 4; ++ct) {
        acc[ct] = (f32x4){0.f, 0.f, 0.f, 0.f};
#pragma unroll
        for (int ks = 0; ks < 2; ++ks)
            acc[ct] = __builtin_amdgcn_mfma_f32_16x16x32_bf16(af[ks], bf[ct][ks], acc[ct], 0, 0, 0);
    }

    // D layout: col = lane&15 (=n), row = quad*4 + reg
#pragma unroll
    for (int ct = 0; ct < 4; ++ct)
#pragma unroll
        for (int r = 0; r < 4; ++r) {
            int rowm = m0 + quad * 4 + r;
            if (rowm < N)
                G[(size_t)rowm * 64 + ct * 16 + n] = f2bf(acc[ct][r]);
        }
}

// SpMM: out[row] += val * G[col]. Sorted rows.
// Per 64-edge chunk: 3 coalesced metadata loads, then readlane-broadcast so
// (r,c,v) are wave-uniform SGPRs -> scalar flush branch, SGPR gather base.
// 16 gathers issued before first consume -> 16 outstanding VMEM per wave.
__global__ __launch_bounds__(256) void k_spmm(const unsigned short* __restrict__ G,
                                              const int* __restrict__ erow,
                                              const int* __restrict__ ecol,
                                              const float* __restrict__ evalv,
                                              float* __restrict__ out,
                                              int E, int cpw) {
    int wave = blockIdx.x * 4 + (threadIdx.x >> 6);
    int lane = threadIdx.x & 63;
    long base0 = (long)wave * cpw * 64;
    if (base0 >= E) return;

    int cur = __builtin_amdgcn_readfirstlane(erow[base0]);
    float acc = 0.f;

    for (int ch = 0; ch < cpw; ++ch) {
        long base = base0 + (long)ch * 64;
        if (base >= E) break;
        long idx = base + lane;
        long cidx = idx < E ? idx : (long)(E - 1);
        int rv = erow[cidx];
        int cv = ecol[cidx];
        float vvf = (idx < E) ? evalv[cidx] : 0.f;
        int vv = __float_as_int(vvf);

#pragma unroll
        for (int j0 = 0; j0 < 64; j0 += 16) {
            float g[16];
#pragma unroll
            for (int u = 0; u < 16; ++u) {
                int c = __builtin_amdgcn_readlane(cv, j0 + u);   // SGPR
                g[u] = bf2f(G[((size_t)(unsigned)c << 6) | (unsigned)lane]);
            }
#pragma unroll
            for (int u = 0; u < 16; ++u) {
                int r = __builtin_amdgcn_readlane(rv, j0 + u);   // SGPR
                float v = __int_as_float(__builtin_amdgcn_readlane(vv, j0 + u));
                if (r != cur) {                                   // scalar branch
                    atomicAdd(out + ((size_t)(unsigned)cur << 6) + lane, acc);
                    acc = 0.f;
                    cur = r;
                }
                acc = fmaf(v, g[u], acc);
            }
        }
    }
    atomicAdd(out + ((size_t)(unsigned)cur << 6) + lane, acc);
}

// Fallback if ws too small: fused f32 gather + shfl transform at flush.
__global__ __launch_bounds__(256) void k_fused(const float* __restrict__ feat,
                                               const int* __restrict__ erow,
                                               const int* __restrict__ ecol,
                                               const float* __restrict__ evalv,
                                               const float* __restrict__ W,
                                               float* __restrict__ out,
                                               int E, int epw) {
    __shared__ float Wt[64 * 64];
    for (int i = threadIdx.x; i < 4096; i += 256) {
        int c = i >> 6, f = i & 63;
        Wt[f * 64 + c] = W[i];
    }
    __syncthreads();

    int wave = blockIdx.x * 4 + (threadIdx.x >> 6);
    int lane = threadIdx.x & 63;
    long e0 = (long)wave * epw;
    if (e0 >= E) return;
    long e1 = e0 + epw; if (e1 > E) e1 = E;

    int cur = erow[e0];
    float acc = 0.f;
    for (long e = e0; e < e1; ++e) {
        int r = erow[e];
        int c = ecol[e];
        float v = evalv[e];
        float g = feat[((size_t)c << 6) | lane];
        if (r != cur) {
            float res = 0.f;
#pragma unroll
            for (int f = 0; f < 64; ++f)
                res += __shfl(acc, f, 64) * Wt[f * 64 + lane];
            atomicAdd(out + ((size_t)cur << 6) + lane, res);
            acc = 0.f;
            cur = r;
        }
        acc += v * g;
    }
    {
        float res = 0.f;
#pragma unroll
        for (int f = 0; f < 64; ++f)
            res += __shfl(acc, f, 64) * Wt[f * 64 + lane];
        atomicAdd(out + ((size_t)cur << 6) + lane, res);
    }
}

extern "C" void kernel_launch(void* const* d_in, const int* in_sizes, int n_in,
                              void* d_out, int out_size, void* d_ws, size_t ws_size,
                              hipStream_t stream) {
    const float* feat  = (const float*)d_in[0];
    const int*   erow  = (const int*)d_in[1];
    const int*   ecol  = (const int*)d_in[2];
    const float* evalv = (const float*)d_in[3];
    const float* W     = (const float*)d_in[4];
    const float* bias  = (const float*)d_in[5];
    float* out = (float*)d_out;

    int N = in_sizes[0] / 64;
    int E = in_sizes[1];

    size_t need = (size_t)N * 64 * sizeof(unsigned short);
    if (ws_size >= need) {
        unsigned short* G = (unsigned short*)d_ws;
        int tiles = (N + 15) / 16;
        int gblocks = (tiles + 3) / 4;
        long total4 = (long)N * 16;
        int iblocks = (int)((total4 + 255) / 256);
        k_setup<<<gblocks + iblocks, 256, 0, stream>>>(feat, W, bias, G, out, N, gblocks);

        const int cpw = 4;                       // 64-edge chunks per wave
        int nchunks = (E + 63) / 64;
        int nwaves = (nchunks + cpw - 1) / cpw;
        int nblocks = (nwaves + 3) / 4;
        k_spmm<<<nblocks, 256, 0, stream>>>(G, erow, ecol, evalv, out, E, cpw);
    } else {
        long total4 = (long)N * 16;
        k_init<<<(int)((total4 + 255) / 256), 256, 0, stream>>>(bias, out, total4);
        int epw = (E + 8191) / 8192;
        if (epw < 32) epw = 32;
        int nwaves = (E + epw - 1) / epw;
        int nblocks = (nwaves + 3) / 4;
        k_fused<<<nblocks, 256, 0, stream>>>(feat, erow, ecol, evalv, W, out, E, epw);
    }
}